// Round 1
// baseline (350.137 us; speedup 1.0000x reference)
//
#include <hip/hip_runtime.h>

#define FDIM 128

typedef __attribute__((ext_vector_type(8))) short bf16x8;
typedef __attribute__((ext_vector_type(4))) float f32x4;

__device__ __forceinline__ unsigned short f2bf(float f){
  // round-to-nearest-even fp32 -> bf16
  unsigned int u = __float_as_uint(f);
  unsigned int r = u + 0x7FFFu + ((u >> 16) & 1u);
  return (unsigned short)(r >> 16);
}

// ---------------- CSR build ----------------
__global__ void k_degree(const int* __restrict__ dst, int* __restrict__ cnt, int E){
  int e = blockIdx.x*256 + threadIdx.x;
  if (e < E) atomicAdd(&cnt[dst[e]], 1);
}

__global__ void k_scan_blocks(const int* __restrict__ cnt, int* __restrict__ excl,
                              int* __restrict__ partials, int N){
  __shared__ int s[256];
  int tid = threadIdx.x;
  int i = blockIdx.x*256 + tid;
  int v = (i < N) ? cnt[i] : 0;
  s[tid] = v; __syncthreads();
  for (int off = 1; off < 256; off <<= 1){
    int t = (tid >= off) ? s[tid - off] : 0;
    __syncthreads();
    s[tid] += t;
    __syncthreads();
  }
  if (i < N) excl[i] = s[tid] - v;        // exclusive within block
  if (tid == 255) partials[blockIdx.x] = s[255];
}

__global__ void k_scan_partials(int* __restrict__ partials, int nb){
  __shared__ int s[512];
  int tid = threadIdx.x;
  int v = (tid < nb) ? partials[tid] : 0;
  s[tid] = v; __syncthreads();
  for (int off = 1; off < 512; off <<= 1){
    int t = (tid >= off) ? s[tid - off] : 0;
    __syncthreads();
    s[tid] += t;
    __syncthreads();
  }
  if (tid < nb) partials[tid] = s[tid] - v; // exclusive block offsets
}

__global__ void k_finalize(int* __restrict__ row_off, const int* __restrict__ partials,
                           const int* __restrict__ cnt, int* __restrict__ cursor,
                           float* __restrict__ inv_deg, int N){
  int i = blockIdx.x*256 + threadIdx.x;
  if (i >= N) return;
  int ro = row_off[i] + partials[blockIdx.x];
  row_off[i] = ro;
  cursor[i]  = ro;
  int c = cnt[i];
  inv_deg[i] = 1.0f / (float)(c > 1 ? c : 1);
}

__global__ void k_fill(const int* __restrict__ src, const int* __restrict__ dst,
                       int* __restrict__ cursor, int* __restrict__ csr_src, int E){
  int e = blockIdx.x*256 + threadIdx.x;
  if (e >= E) return;
  int d = dst[e];
  int pos = atomicAdd(&cursor[d], 1);
  csr_src[pos] = src[e];
}

// ---------------- weight pre-convert: Wcat[layer][256][128] bf16 ----------------
// rows 0..127 = Wl (z columns), rows 128..255 = Wr (self columns)
__global__ void k_wcat(const float* __restrict__ Wl0, const float* __restrict__ Wr0,
                       const float* __restrict__ Wl1, const float* __restrict__ Wr1,
                       unsigned short* __restrict__ Wcat){
  int i = blockIdx.x*256 + threadIdx.x;
  if (i >= 2*256*128) return;
  int l   = i >> 15;          // 32768 per layer
  int rem = i & 32767;
  int row = rem >> 7, k = rem & 127;
  const float* W = (l == 0) ? ((row < 128) ? Wl0 : Wr0)
                            : ((row < 128) ? Wl1 : Wr1);
  Wcat[i] = f2bf(W[(row & 127)*128 + k]);
}

// ---------------- dual GEMM: Z = X@Wl^T (bf16), S = X@Wr^T + (bl+br) (bf16) ----------------
// block = 256 threads (4 waves). Block processes 64 rows x 256 cols (z:128 | self:128).
// Wave w owns col-tiles ct = 4w..4w+3; B fragments live in VGPRs across the
// grid-stride row-block loop. X tile staged to LDS as bf16 with XOR-chunk swizzle.
__global__ __launch_bounds__(256, 2)
void k_dualgemm(const float* __restrict__ X, const unsigned short* __restrict__ Wcat,
                const float* __restrict__ bl, const float* __restrict__ br,
                unsigned short* __restrict__ Z, unsigned short* __restrict__ S,
                int N, int nrb){
  __shared__ unsigned short lds[64*FDIM]; // 64 rows x 128 bf16 = 16 KiB
  const int tid  = threadIdx.x;
  const int wave = tid >> 6;
  const int lane = tid & 63;
  const int n = lane & 15, q = lane >> 4;

  // preload B fragments: [ct_local][kk], each lane: Wcat row ct*16+n, k = kk*32 + q*8 .. +8
  bf16x8 bfrag[4][4];
#pragma unroll
  for (int ctl = 0; ctl < 4; ctl++){
    int row = (wave*4 + ctl)*16 + n;
#pragma unroll
    for (int kk = 0; kk < 4; kk++){
      const unsigned short* p = Wcat + row*FDIM + kk*32 + q*8;
      bfrag[ctl][kk] = *(const bf16x8*)p;
    }
  }
  // bias (only self col-tiles, ct >= 8)
  float bias[4];
#pragma unroll
  for (int ctl = 0; ctl < 4; ctl++){
    int ct = wave*4 + ctl;
    if (ct >= 8){ int col = (ct - 8)*16 + n; bias[ctl] = bl[col] + br[col]; }
    else bias[ctl] = 0.0f;
  }

  for (int rb = blockIdx.x; rb < nrb; rb += gridDim.x){
    int row0 = rb*64;
    __syncthreads();  // protect LDS from previous iteration's readers
    // stage A tile: 64 rows x 16 chunks (chunk = 8 bf16 = 16B), swizzled c16 ^= (row&15)
#pragma unroll
    for (int it = 0; it < 4; it++){
      int cu  = tid + it*256;
      int r   = cu >> 4, c16 = cu & 15;
      int gr  = row0 + r;
      float4 v0, v1;
      if (gr < N){
        const float4* sp = (const float4*)(X + (size_t)gr*FDIM + c16*8);
        v0 = sp[0]; v1 = sp[1];
      } else {
        v0 = make_float4(0,0,0,0); v1 = make_float4(0,0,0,0);
      }
      bf16x8 p;
      p[0] = (short)f2bf(v0.x); p[1] = (short)f2bf(v0.y);
      p[2] = (short)f2bf(v0.z); p[3] = (short)f2bf(v0.w);
      p[4] = (short)f2bf(v1.x); p[5] = (short)f2bf(v1.y);
      p[6] = (short)f2bf(v1.z); p[7] = (short)f2bf(v1.w);
      *(bf16x8*)(lds + r*FDIM + ((c16 ^ (r & 15)) * 8)) = p;
    }
    __syncthreads();

    f32x4 acc[4][4];
#pragma unroll
    for (int rt = 0; rt < 4; rt++)
#pragma unroll
      for (int ctl = 0; ctl < 4; ctl++)
        acc[rt][ctl] = (f32x4){0.f, 0.f, 0.f, 0.f};

#pragma unroll
    for (int kk = 0; kk < 4; kk++){
      bf16x8 afr[4];
#pragma unroll
      for (int rt = 0; rt < 4; rt++){
        int r = rt*16 + n;
        int c16 = (kk*4 + q) ^ n;   // (r & 15) == n
        afr[rt] = *(const bf16x8*)(lds + r*FDIM + c16*8);
      }
#pragma unroll
      for (int rt = 0; rt < 4; rt++)
#pragma unroll
        for (int ctl = 0; ctl < 4; ctl++)
          acc[rt][ctl] = __builtin_amdgcn_mfma_f32_16x16x32_bf16(
              afr[rt], bfrag[ctl][kk], acc[rt][ctl], 0, 0, 0);
    }

    // store: D col = lane&15, row = q*4 + reg
#pragma unroll
    for (int rt = 0; rt < 4; rt++){
#pragma unroll
      for (int ctl = 0; ctl < 4; ctl++){
        int ct = wave*4 + ctl;
#pragma unroll
        for (int r = 0; r < 4; r++){
          int grow = row0 + rt*16 + q*4 + r;
          if (grow < N){
            float v = acc[rt][ctl][r];
            if (ct < 8){
              Z[(size_t)grow*FDIM + ct*16 + n] = f2bf(v);
            } else {
              S[(size_t)grow*FDIM + (ct - 8)*16 + n] = f2bf(v + bias[ctl]);
            }
          }
        }
      }
    }
  }
}

// ---------------- aggregate + finish: out = relu(sum(Z[src])/deg + S) ----------------
// one wave per node; lane covers features 2l, 2l+1 (one dword of bf16 pair)
__global__ __launch_bounds__(256)
void k_aggregate(const unsigned short* __restrict__ Z, const unsigned short* __restrict__ S,
                 const int* __restrict__ row_off, const int* __restrict__ cnt,
                 const float* __restrict__ inv_deg, const int* __restrict__ csr_src,
                 float* __restrict__ Out, int N){
  int wave = threadIdx.x >> 6, lane = threadIdx.x & 63;
  int node = blockIdx.x*4 + wave;
  if (node >= N) return;
  int start = row_off[node];
  int deg   = cnt[node];
  float inv = inv_deg[node];
  float a0 = 0.f, a1 = 0.f;
  for (int base = 0; base < deg; base += 64){
    int e = base + lane;
    int s = (e < deg) ? csr_src[start + e] : 0;
    int m = deg - base; if (m > 64) m = 64;
    for (int j = 0; j < m; j++){
      int sj = __shfl(s, j);
      unsigned int v = *(const unsigned int*)(Z + (size_t)sj*FDIM + lane*2);
      a0 += __uint_as_float(v << 16);
      a1 += __uint_as_float(v & 0xFFFF0000u);
    }
  }
  unsigned int sv = *(const unsigned int*)(S + (size_t)node*FDIM + lane*2);
  float o0 = a0*inv + __uint_as_float(sv << 16);
  float o1 = a1*inv + __uint_as_float(sv & 0xFFFF0000u);
  o0 = fmaxf(o0, 0.f); o1 = fmaxf(o1, 0.f);
  *(float2*)(Out + (size_t)node*FDIM + lane*2) = make_float2(o0, o1);
}

extern "C" void kernel_launch(void* const* d_in, const int* in_sizes, int n_in,
                              void* d_out, int out_size, void* d_ws, size_t ws_size,
                              hipStream_t stream){
  const float* x   = (const float*)d_in[0];
  const int*   eix = (const int*)d_in[1];
  const float* Wl0 = (const float*)d_in[2];
  const float* bl0 = (const float*)d_in[3];
  const float* Wr0 = (const float*)d_in[4];
  const float* br0 = (const float*)d_in[5];
  const float* Wl1 = (const float*)d_in[6];
  const float* bl1 = (const float*)d_in[7];
  const float* Wr1 = (const float*)d_in[8];
  const float* br1 = (const float*)d_in[9];
  float* out = (float*)d_out;

  int N = in_sizes[0] / FDIM;
  int E = in_sizes[1] / 2;
  const int* src = eix;
  const int* dst = eix + E;

  // workspace layout
  unsigned short* Z    = (unsigned short*)d_ws;
  unsigned short* S    = Z + (size_t)N*FDIM;
  unsigned short* Wcat = S + (size_t)N*FDIM;
  int*   cnt     = (int*)(Wcat + 2*256*128);
  int*   row_off = cnt + N;
  int*   cursor  = row_off + N;
  float* inv_deg = (float*)(cursor + N);
  int*   csr_src = (int*)(inv_deg + N);
  int*   partials= csr_src + E;

  int nb = (N + 255)/256;

  hipMemsetAsync(cnt, 0, (size_t)N*sizeof(int), stream);
  k_degree       <<<(E + 255)/256, 256, 0, stream>>>(dst, cnt, E);
  k_scan_blocks  <<<nb, 256, 0, stream>>>(cnt, row_off, partials, N);
  k_scan_partials<<<1, 512, 0, stream>>>(partials, nb);
  k_finalize     <<<nb, 256, 0, stream>>>(row_off, partials, cnt, cursor, inv_deg, N);
  k_fill         <<<(E + 255)/256, 256, 0, stream>>>(src, dst, cursor, csr_src, E);
  k_wcat         <<<(2*256*128 + 255)/256, 256, 0, stream>>>(Wl0, Wr0, Wl1, Wr1, Wcat);

  int nrb = (N + 63)/64;
  // layer 1
  k_dualgemm <<<512, 256, 0, stream>>>(x, Wcat, bl0, br0, Z, S, N, nrb);
  k_aggregate<<<(N + 3)/4, 256, 0, stream>>>(Z, S, row_off, cnt, inv_deg, csr_src, out, N);
  // layer 2 (reads h from d_out, writes final to d_out)
  k_dualgemm <<<512, 256, 0, stream>>>(out, Wcat + 256*128, bl1, br1, Z, S, N, nrb);
  k_aggregate<<<(N + 3)/4, 256, 0, stream>>>(Z, S, row_off, cnt, inv_deg, csr_src, out, N);
}

// Round 3
// 307.326 us; speedup vs baseline: 1.1393x; 1.1393x over previous
//
#include <hip/hip_runtime.h>

#define FDIM 128

typedef __attribute__((ext_vector_type(8))) short bf16x8;
typedef __attribute__((ext_vector_type(4))) float f32x4;

__device__ __forceinline__ unsigned short f2bf(float f){
  // round-to-nearest-even fp32 -> bf16
  unsigned int u = __float_as_uint(f);
  unsigned int r = u + 0x7FFFu + ((u >> 16) & 1u);
  return (unsigned short)(r >> 16);
}

// ---------------- CSR build ----------------
__global__ void k_degree(const int* __restrict__ dst, int* __restrict__ cnt, int E){
  int e = blockIdx.x*256 + threadIdx.x;
  if (e < E) atomicAdd(&cnt[dst[e]], 1);
}

__global__ void k_scan_blocks(const int* __restrict__ cnt, int* __restrict__ excl,
                              int* __restrict__ partials, int N){
  __shared__ int s[256];
  int tid = threadIdx.x;
  int i = blockIdx.x*256 + tid;
  int v = (i < N) ? cnt[i] : 0;
  s[tid] = v; __syncthreads();
  for (int off = 1; off < 256; off <<= 1){
    int t = (tid >= off) ? s[tid - off] : 0;
    __syncthreads();
    s[tid] += t;
    __syncthreads();
  }
  if (i < N) excl[i] = s[tid] - v;        // exclusive within block
  if (tid == 255) partials[blockIdx.x] = s[255];
}

__global__ void k_scan_partials(int* __restrict__ partials, int nb){
  __shared__ int s[512];
  int tid = threadIdx.x;
  int v = (tid < nb) ? partials[tid] : 0;
  s[tid] = v; __syncthreads();
  for (int off = 1; off < 512; off <<= 1){
    int t = (tid >= off) ? s[tid - off] : 0;
    __syncthreads();
    s[tid] += t;
    __syncthreads();
  }
  if (tid < nb) partials[tid] = s[tid] - v; // exclusive block offsets
}

__global__ void k_finalize(int* __restrict__ row_off, const int* __restrict__ partials,
                           const int* __restrict__ cnt, int* __restrict__ cursor,
                           float* __restrict__ inv_deg, int N){
  int i = blockIdx.x*256 + threadIdx.x;
  if (i >= N) return;
  int ro = row_off[i] + partials[blockIdx.x];
  row_off[i] = ro;
  cursor[i]  = ro;
  int c = cnt[i];
  inv_deg[i] = 1.0f / (float)(c > 1 ? c : 1);
}

__global__ void k_fill(const int* __restrict__ src, const int* __restrict__ dst,
                       int* __restrict__ cursor, int* __restrict__ csr_src, int E){
  int e = blockIdx.x*256 + threadIdx.x;
  if (e >= E) return;
  int d = dst[e];
  int pos = atomicAdd(&cursor[d], 1);
  csr_src[pos] = src[e];
}

// ---------------- weight pre-convert: Wcat[layer][256][128] bf16 ----------------
__global__ void k_wcat(const float* __restrict__ Wl0, const float* __restrict__ Wr0,
                       const float* __restrict__ Wl1, const float* __restrict__ Wr1,
                       unsigned short* __restrict__ Wcat){
  int i = blockIdx.x*256 + threadIdx.x;
  if (i >= 2*256*128) return;
  int l   = i >> 15;
  int rem = i & 32767;
  int row = rem >> 7, k = rem & 127;
  const float* W = (l == 0) ? ((row < 128) ? Wl0 : Wr0)
                            : ((row < 128) ? Wl1 : Wr1);
  Wcat[i] = f2bf(W[(row & 127)*128 + k]);
}

// ---------------- dual GEMM: Z = X@Wl^T (bf16), S = X@Wr^T + (bl+br) (bf16) ----------------
// block = 256 threads (4 waves); 64 rows x 256 cols (z:128 | self:128) per block.
// A_BF16: X is bf16 (layer 2's h); else fp32 (layer 1's x).
template<bool A_BF16>
__global__ __launch_bounds__(256, 2)
void k_dualgemm(const void* __restrict__ Xv, const unsigned short* __restrict__ Wcat,
                const float* __restrict__ bl, const float* __restrict__ br,
                unsigned short* __restrict__ Z, unsigned short* __restrict__ S,
                int N, int nrb){
  __shared__ unsigned short lds[64*FDIM]; // 16 KiB
  const int tid  = threadIdx.x;
  const int wave = tid >> 6;
  const int lane = tid & 63;
  const int n = lane & 15, q = lane >> 4;

  bf16x8 bfrag[4][4];
#pragma unroll
  for (int ctl = 0; ctl < 4; ctl++){
    int row = (wave*4 + ctl)*16 + n;
#pragma unroll
    for (int kk = 0; kk < 4; kk++){
      const unsigned short* p = Wcat + row*FDIM + kk*32 + q*8;
      bfrag[ctl][kk] = *(const bf16x8*)p;
    }
  }
  float bias[4];
#pragma unroll
  for (int ctl = 0; ctl < 4; ctl++){
    int ct = wave*4 + ctl;
    if (ct >= 8){ int col = (ct - 8)*16 + n; bias[ctl] = bl[col] + br[col]; }
    else bias[ctl] = 0.0f;
  }

  for (int rb = blockIdx.x; rb < nrb; rb += gridDim.x){
    int row0 = rb*64;
    __syncthreads();
#pragma unroll
    for (int it = 0; it < 4; it++){
      int cu  = tid + it*256;
      int r   = cu >> 4, c16 = cu & 15;
      int gr  = row0 + r;
      bf16x8 p;
      if (gr < N){
        if constexpr (A_BF16){
          const unsigned short* X = (const unsigned short*)Xv;
          p = *(const bf16x8*)(X + (size_t)gr*FDIM + c16*8);
        } else {
          const float* X = (const float*)Xv;
          const float4* sp = (const float4*)(X + (size_t)gr*FDIM + c16*8);
          float4 v0 = sp[0], v1 = sp[1];
          p[0] = (short)f2bf(v0.x); p[1] = (short)f2bf(v0.y);
          p[2] = (short)f2bf(v0.z); p[3] = (short)f2bf(v0.w);
          p[4] = (short)f2bf(v1.x); p[5] = (short)f2bf(v1.y);
          p[6] = (short)f2bf(v1.z); p[7] = (short)f2bf(v1.w);
        }
      } else {
#pragma unroll
        for (int z = 0; z < 8; z++) p[z] = 0;
      }
      *(bf16x8*)(lds + r*FDIM + ((c16 ^ (r & 15)) * 8)) = p;
    }
    __syncthreads();

    f32x4 acc[4][4];
#pragma unroll
    for (int rt = 0; rt < 4; rt++)
#pragma unroll
      for (int ctl = 0; ctl < 4; ctl++)
        acc[rt][ctl] = (f32x4){0.f, 0.f, 0.f, 0.f};

#pragma unroll
    for (int kk = 0; kk < 4; kk++){
      bf16x8 afr[4];
#pragma unroll
      for (int rt = 0; rt < 4; rt++){
        int r = rt*16 + n;
        int c16 = (kk*4 + q) ^ n;
        afr[rt] = *(const bf16x8*)(lds + r*FDIM + c16*8);
      }
#pragma unroll
      for (int rt = 0; rt < 4; rt++)
#pragma unroll
        for (int ctl = 0; ctl < 4; ctl++)
          acc[rt][ctl] = __builtin_amdgcn_mfma_f32_16x16x32_bf16(
              afr[rt], bfrag[ctl][kk], acc[rt][ctl], 0, 0, 0);
    }

#pragma unroll
    for (int rt = 0; rt < 4; rt++){
#pragma unroll
      for (int ctl = 0; ctl < 4; ctl++){
        int ct = wave*4 + ctl;
#pragma unroll
        for (int r = 0; r < 4; r++){
          int grow = row0 + rt*16 + q*4 + r;
          if (grow < N){
            float v = acc[rt][ctl][r];
            if (ct < 8){
              Z[(size_t)grow*FDIM + ct*16 + n] = f2bf(v);
            } else {
              S[(size_t)grow*FDIM + (ct - 8)*16 + n] = f2bf(v + bias[ctl]);
            }
          }
        }
      }
    }
  }
}

// ---------------- aggregate + finish: out = relu(sum(Z[src])/deg + S) ----------------
// One wave per node; lane covers features 2l, 2l+1 (one dword = bf16 pair).
// Index list loaded per-lane (guarded), then batched shfl x8 -> 8 independent
// gathers in flight. All indices/extents clamped so no OOB is possible.
template<bool OUT_BF16>
__global__ __launch_bounds__(256)
void k_aggregate(const unsigned short* __restrict__ Z, const unsigned short* __restrict__ S,
                 const int* __restrict__ row_off, const int* __restrict__ cnt,
                 const float* __restrict__ inv_deg, const int* __restrict__ csr_src,
                 void* __restrict__ OutV, int N, int E){
  int wave = threadIdx.x >> 6, lane = threadIdx.x & 63;
  int node = blockIdx.x*4 + wave;
  if (node >= N) return;
  int start = row_off[node];
  int deg   = cnt[node];
  // defensive clamps: make OOB impossible regardless of CSR state
  if (start < 0) start = 0;
  if (start > E) start = E;
  if (deg < 0) deg = 0;
  if (start + deg > E) deg = E - start;
  float inv = inv_deg[node];
  unsigned int sv = *(const unsigned int*)(S + (size_t)node*FDIM + lane*2);

  const int* cb = csr_src + start;
  float a0 = 0.f, a1 = 0.f;
  for (int base = 0; base < deg; base += 64){
    int m = deg - base; if (m > 64) m = 64;
    int sidx = (lane < m) ? cb[base + lane] : 0;   // per-lane guarded load
    for (int j = 0; j < m; j += 8){
      int id[8];
#pragma unroll
      for (int t = 0; t < 8; t++){
        int sl = j + t; if (sl >= m) sl = 0;       // uniform clamp of shfl src lane
        id[t] = __shfl(sidx, sl);                  // 8 independent bpermutes
      }
      unsigned int v[8];
#pragma unroll
      for (int t = 0; t < 8; t++){
        unsigned int u = (unsigned int)id[t];
        if (u >= (unsigned int)N) u = 0;           // defensive index clamp
        v[t] = *(const unsigned int*)(Z + (size_t)u*FDIM + lane*2);  // 8 loads in flight
      }
#pragma unroll
      for (int t = 0; t < 8; t++){
        if (j + t < m){                            // uniform accumulate mask
          a0 += __uint_as_float(v[t] << 16);
          a1 += __uint_as_float(v[t] & 0xFFFF0000u);
        }
      }
    }
  }
  float o0 = fmaxf(a0*inv + __uint_as_float(sv << 16), 0.f);
  float o1 = fmaxf(a1*inv + __uint_as_float(sv & 0xFFFF0000u), 0.f);
  if constexpr (OUT_BF16){
    unsigned int pk = ((unsigned int)f2bf(o1) << 16) | (unsigned int)f2bf(o0);
    ((unsigned int*)OutV)[(size_t)node*64 + lane] = pk;
  } else {
    ((float2*)OutV)[(size_t)node*64 + lane] = make_float2(o0, o1);
  }
}

extern "C" void kernel_launch(void* const* d_in, const int* in_sizes, int n_in,
                              void* d_out, int out_size, void* d_ws, size_t ws_size,
                              hipStream_t stream){
  const float* x   = (const float*)d_in[0];
  const int*   eix = (const int*)d_in[1];
  const float* Wl0 = (const float*)d_in[2];
  const float* bl0 = (const float*)d_in[3];
  const float* Wr0 = (const float*)d_in[4];
  const float* br0 = (const float*)d_in[5];
  const float* Wl1 = (const float*)d_in[6];
  const float* bl1 = (const float*)d_in[7];
  const float* Wr1 = (const float*)d_in[8];
  const float* br1 = (const float*)d_in[9];
  float* out = (float*)d_out;

  int N = in_sizes[0] / FDIM;
  int E = in_sizes[1] / 2;
  const int* src = eix;
  const int* dst = eix + E;

  // workspace layout
  unsigned short* Z    = (unsigned short*)d_ws;
  unsigned short* S    = Z + (size_t)N*FDIM;
  unsigned short* Wcat = S + (size_t)N*FDIM;
  int*   cnt     = (int*)(Wcat + 2*256*128);
  int*   row_off = cnt + N;
  int*   cursor  = row_off + N;
  float* inv_deg = (float*)(cursor + N);
  int*   csr_src = (int*)(inv_deg + N);
  int*   partials= csr_src + E;

  // layer-1 hidden h stored as bf16 in the first half of d_out (overwritten later)
  unsigned short* H = (unsigned short*)d_out;

  int nb = (N + 255)/256;

  hipMemsetAsync(cnt, 0, (size_t)N*sizeof(int), stream);
  k_degree       <<<(E + 255)/256, 256, 0, stream>>>(dst, cnt, E);
  k_scan_blocks  <<<nb, 256, 0, stream>>>(cnt, row_off, partials, N);
  k_scan_partials<<<1, 512, 0, stream>>>(partials, nb);
  k_finalize     <<<nb, 256, 0, stream>>>(row_off, partials, cnt, cursor, inv_deg, N);
  k_fill         <<<(E + 255)/256, 256, 0, stream>>>(src, dst, cursor, csr_src, E);
  k_wcat         <<<(2*256*128 + 255)/256, 256, 0, stream>>>(Wl0, Wr0, Wl1, Wr1, Wcat);

  int nrb = (N + 63)/64;
  // layer 1: x (fp32) -> Z,S -> h (bf16, in d_out)
  k_dualgemm<false> <<<512, 256, 0, stream>>>(x, Wcat, bl0, br0, Z, S, N, nrb);
  k_aggregate<true> <<<(N + 3)/4, 256, 0, stream>>>(Z, S, row_off, cnt, inv_deg, csr_src, H, N, E);
  // layer 2: h (bf16) -> Z,S -> out (fp32)
  k_dualgemm<true>  <<<512, 256, 0, stream>>>(H, Wcat + 256*128, bl1, br1, Z, S, N, nrb);
  k_aggregate<false><<<(N + 3)/4, 256, 0, stream>>>(Z, S, row_off, cnt, inv_deg, csr_src, out, N, E);
}